// Round 5
// baseline (277.872 us; speedup 1.0000x reference)
//
#include <hip/hip_runtime.h>
#include <hip/hip_bf16.h>
#include <cstdint>
#include <cstddef>

#define NV    8192   // nodes
#define KIN   512    // in features
#define MOUT  128    // out features
#define LOG2E 1.4426950408889634f

typedef __attribute__((ext_vector_type(4))) float f32x4;
typedef __attribute__((ext_vector_type(8))) short short8;

__device__ __forceinline__ unsigned short f2bf(float x) {
  unsigned int u = __float_as_uint(x);
  return (unsigned short)((u + 0x7fffu + ((u >> 16) & 1u)) >> 16);  // RNE
}
__device__ __forceinline__ float elu1(float x) { return x > 0.f ? x : expm1f(x); }

// ---------------- kernel 1: wh = h @ w^T (fp32) + fused wh1/wh2 (log2-scaled) ----------------
__global__ __launch_bounds__(256) void k_wh(const float* __restrict__ h,
                                            const float* __restrict__ w,
                                            const float* __restrict__ a1,
                                            const float* __restrict__ a2,
                                            float* __restrict__ wh,
                                            float* __restrict__ wh1,
                                            float* __restrict__ wh2) {
  __shared__ __align__(16) float hT[64][36];
  __shared__ __align__(16) float wT[64][128];
  const int t = threadIdx.x;
  const int row0 = blockIdx.x * 32;
  const int hr = t >> 3, hu = t & 7;
  const int wc = t >> 1, whalf = t & 1;
  const int cg = t & 31, rg = t >> 5;
  const int c0 = cg * 4, r0 = rg * 4;
  float acc[4][4] = {};

  for (int kt = 0; kt < 8; ++kt) {
    const int k0 = kt * 64;
    __syncthreads();
#pragma unroll
    for (int v = 0; v < 8; ++v)
      hT[hu + 8 * v][hr] = h[(size_t)(row0 + hr) * KIN + k0 + hu + 8 * v];
#pragma unroll
    for (int mv = 0; mv < 8; ++mv) {
      const float4 wv = *(const float4*)&w[(size_t)wc * KIN + k0 + whalf * 32 + mv * 4];
      wT[whalf * 32 + mv * 4 + 0][wc] = wv.x;
      wT[whalf * 32 + mv * 4 + 1][wc] = wv.y;
      wT[whalf * 32 + mv * 4 + 2][wc] = wv.z;
      wT[whalf * 32 + mv * 4 + 3][wc] = wv.w;
    }
    __syncthreads();
#pragma unroll 8
    for (int kk = 0; kk < 64; ++kk) {
      const float4 hv = *(const float4*)&hT[kk][r0];
      const float4 wv = *(const float4*)&wT[kk][c0];
      const float hvv[4] = {hv.x, hv.y, hv.z, hv.w};
      const float wvv[4] = {wv.x, wv.y, wv.z, wv.w};
#pragma unroll
      for (int i = 0; i < 4; ++i)
#pragma unroll
        for (int j = 0; j < 4; ++j)
          acc[i][j] = fmaf(hvv[i], wvv[j], acc[i][j]);
    }
  }

  const float4 a1v = *(const float4*)&a1[c0];
  const float4 a2v = *(const float4*)&a2[c0];
#pragma unroll
  for (int i = 0; i < 4; ++i) {
    float4 o;
    o.x = acc[i][0]; o.y = acc[i][1]; o.z = acc[i][2]; o.w = acc[i][3];
    *(float4*)&wh[(size_t)(row0 + r0 + i) * MOUT + c0] = o;
    float s1 = acc[i][0] * a1v.x + acc[i][1] * a1v.y + acc[i][2] * a1v.z + acc[i][3] * a1v.w;
    float s2 = acc[i][0] * a2v.x + acc[i][1] * a2v.y + acc[i][2] * a2v.z + acc[i][3] * a2v.w;
#pragma unroll
    for (int off = 16; off > 0; off >>= 1) {
      s1 += __shfl_down(s1, off, 32);
      s2 += __shfl_down(s2, off, 32);
    }
    if (cg == 0) {
      wh1[row0 + r0 + i] = s1 * LOG2E;   // log2-domain scores
      wh2[row0 + r0 + i] = s2 * LOG2E;
    }
  }
}

// ---------------- kernel 2: fragB = bf16(wh) in MFMA-fragment order ----------------
// fragB[jt][cg][ks][lane][e] = bf16(wh[jt*64 + ks*32 + (lane>>4)*8 + e][cg*16 + (lane&15)])
__global__ __launch_bounds__(256) void k_tr(const float* __restrict__ wh,
                                            unsigned short* __restrict__ fragB) {
  __shared__ __align__(16) unsigned short ldsT[128][72];
  const int t = threadIdx.x;
  const int j0 = blockIdx.x * 64;
  {
    const int jr = t >> 2, q = t & 3;
#pragma unroll
    for (int mv = 0; mv < 8; ++mv) {
      const float4 v = *(const float4*)&wh[(size_t)(j0 + jr) * MOUT + q * 32 + mv * 4];
      ldsT[q * 32 + mv * 4 + 0][jr] = f2bf(v.x);
      ldsT[q * 32 + mv * 4 + 1][jr] = f2bf(v.y);
      ldsT[q * 32 + mv * 4 + 2][jr] = f2bf(v.z);
      ldsT[q * 32 + mv * 4 + 3][jr] = f2bf(v.w);
    }
  }
  __syncthreads();
  {
#pragma unroll
    for (int k = 0; k < 4; ++k) {
      const int K = k * 256 + t;
      const int cg = K >> 7, ks = (K >> 6) & 1, ln = K & 63;
      const int lg = ln >> 4, l15 = ln & 15;
      const short8 v = *(const short8*)&ldsT[cg * 16 + l15][ks * 32 + lg * 8];
      *(short8*)&fragB[((size_t)blockIdx.x * 1024 + K) * 8] = v;
    }
  }
}

// ---------------- kernel 3: barrier-free partial attention + PV (bf16 MFMA) ----------------
// grid (256, S) x 256 thr, 8 blocks/CU. Wave wv=(ih,ch): 16 i-rows x 64 c-cols.
// P fragment in registers (log2-domain, exp2), B fragments streamed from L2. No LDS.
__global__ __launch_bounds__(256, 8) void k_attn_p(const unsigned short* __restrict__ fragB,
                                                   const int* __restrict__ adj,
                                                   const float* __restrict__ wh1l,
                                                   const float* __restrict__ wh2l,
                                                   float* __restrict__ out_p,
                                                   float* __restrict__ psum_p,
                                                   int ntiles) {
  const int t = threadIdx.x;
  const int i0 = blockIdx.x * 32;
  const int jbase = blockIdx.y * ntiles * 64;
  const int lane = t & 63;
  const int wv = t >> 6;
  const int ih = wv & 1, ch = wv >> 1;
  const int l15 = lane & 15, lg = lane >> 4;

  const int row = i0 + ih * 16 + l15;
  const float wh1r = wh1l[row];
  const int* aptr = adj + (size_t)row * NV + jbase + lg * 8;
  const unsigned short* bptr = fragB + (size_t)(jbase >> 6) * 8192 + ch * 4096 + lane * 8;
  const float* w2ptr = wh2l + jbase + lg * 8;

  f32x4 acc[4] = {};
  float psum = 0.f;

  // prologue: adj prefetch for tile 0
  int4 a0 = *(const int4*)(aptr);
  int4 a1 = *(const int4*)(aptr + 4);
  int4 a2 = *(const int4*)(aptr + 32);
  int4 a3 = *(const int4*)(aptr + 36);
  aptr += 64;

  for (int it = 0; it < ntiles; ++it) {
    // adj values are {0,1}: bit0 == (a>0)
    const unsigned int m =
        (unsigned)(a0.x & 1)        | ((unsigned)(a0.y & 1) << 1)  |
        ((unsigned)(a0.z & 1) << 2) | ((unsigned)(a0.w & 1) << 3)  |
        ((unsigned)(a1.x & 1) << 4) | ((unsigned)(a1.y & 1) << 5)  |
        ((unsigned)(a1.z & 1) << 6) | ((unsigned)(a1.w & 1) << 7)  |
        ((unsigned)(a2.x & 1) << 8) | ((unsigned)(a2.y & 1) << 9)  |
        ((unsigned)(a2.z & 1) << 10)| ((unsigned)(a2.w & 1) << 11) |
        ((unsigned)(a3.x & 1) << 12)| ((unsigned)(a3.y & 1) << 13) |
        ((unsigned)(a3.z & 1) << 14)| ((unsigned)(a3.w & 1) << 15);
    // prefetch next tile's adj (HBM latency hidden across the iteration + TLP)
    if (it + 1 < ntiles) {
      a0 = *(const int4*)(aptr);
      a1 = *(const int4*)(aptr + 4);
      a2 = *(const int4*)(aptr + 32);
      a3 = *(const int4*)(aptr + 36);
      aptr += 64;
    }
#pragma unroll
    for (int ks = 0; ks < 2; ++ks) {
      const short8 bf0 = *(const short8*)(bptr + ks * 512);
      const short8 bf1 = *(const short8*)(bptr + 1024 + ks * 512);
      const short8 bf2 = *(const short8*)(bptr + 2048 + ks * 512);
      const short8 bf3 = *(const short8*)(bptr + 3072 + ks * 512);
      const float4 wa = *(const float4*)(w2ptr + ks * 32);
      const float4 wb = *(const float4*)(w2ptr + ks * 32 + 4);
      const float w2v[8] = {wa.x, wa.y, wa.z, wa.w, wb.x, wb.y, wb.z, wb.w};
      float pe[8];
#pragma unroll
      for (int e = 0; e < 8; ++e) {
        const float x = wh1r + w2v[e];               // log2-domain score
        const float l = fmaxf(x, 0.01f * x);         // leaky relu (scale-commutes)
        const float px = __builtin_amdgcn_exp2f(l);  // 2^l == exp(score)
        pe[e] = ((m >> (ks * 8 + e)) & 1u) ? px : 0.f;
        psum += pe[e];
      }
      union { short8 s8; __hip_bfloat162 h2[4]; } pk;
#pragma unroll
      for (int e = 0; e < 4; ++e)
        pk.h2[e] = __float22bfloat162_rn(make_float2(pe[2 * e], pe[2 * e + 1]));
      const short8 af = pk.s8;
      acc[0] = __builtin_amdgcn_mfma_f32_16x16x32_bf16(af, bf0, acc[0], 0, 0, 0);
      acc[1] = __builtin_amdgcn_mfma_f32_16x16x32_bf16(af, bf1, acc[1], 0, 0, 0);
      acc[2] = __builtin_amdgcn_mfma_f32_16x16x32_bf16(af, bf2, acc[2], 0, 0, 0);
      acc[3] = __builtin_amdgcn_mfma_f32_16x16x32_bf16(af, bf3, acc[3], 0, 0, 0);
    }
    bptr += 8192;
    w2ptr += 64;
  }

  // partial row sums (lanes 16 apart share l15; ch halves both computed full rows)
  psum += __shfl_xor(psum, 16, 64);
  psum += __shfl_xor(psum, 32, 64);
  if (ch == 0 && lg == 0)
    psum_p[(size_t)blockIdx.y * NV + row] = psum;

  // store unnormalized partial tile (C/D: col=l15, row=lg*4+r)
  const size_t ob = ((size_t)blockIdx.y * NV + i0 + ih * 16) * MOUT + ch * 64;
#pragma unroll
  for (int cgl = 0; cgl < 4; ++cgl)
#pragma unroll
    for (int r = 0; r < 4; ++r)
      out_p[ob + (size_t)(lg * 4 + r) * MOUT + cgl * 16 + l15] = acc[cgl][r];
}

// ---------------- kernel 4: combine partials, normalize, ELU ----------------
__global__ __launch_bounds__(256) void k_comb(const float* __restrict__ out_p,
                                              const float* __restrict__ psum_p,
                                              float* __restrict__ out, int S) {
  const int idx = (blockIdx.x * 256 + threadIdx.x) * 4;
  const int n = idx >> 7;  // MOUT = 128
  float denom = 0.f;
  for (int s = 0; s < S; ++s) denom += psum_p[(size_t)s * NV + n];
  float4 acc = {0.f, 0.f, 0.f, 0.f};
  for (int s = 0; s < S; ++s) {
    const float4 v = *(const float4*)&out_p[(size_t)s * NV * MOUT + idx];
    acc.x += v.x; acc.y += v.y; acc.z += v.z; acc.w += v.w;
  }
  const float inv = 1.f / denom;
  float4 o;
  o.x = elu1(acc.x * inv);
  o.y = elu1(acc.y * inv);
  o.z = elu1(acc.z * inv);
  o.w = elu1(acc.w * inv);
  *(float4*)&out[idx] = o;
}

extern "C" void kernel_launch(void* const* d_in, const int* in_sizes, int n_in,
                              void* d_out, int out_size, void* d_ws, size_t ws_size,
                              hipStream_t stream) {
  const float* h  = (const float*)d_in[0];
  const int* adj  = (const int*)d_in[1];
  const float* w  = (const float*)d_in[2];
  const float* a1 = (const float*)d_in[3];
  const float* a2 = (const float*)d_in[4];
  float* out = (float*)d_out;

  char* ws = (char*)d_ws;
  // layout: [fragB 2MB][wh1][wh2][psum_p 8*32KB][region: wh 4MB aliased by out_p slabs]
  unsigned short* fragB = (unsigned short*)ws;
  size_t off = (size_t)MOUT * NV * 2;
  float* wh1 = (float*)(ws + off); off += (size_t)NV * 4;
  float* wh2 = (float*)(ws + off); off += (size_t)NV * 4;
  float* psum_p = (float*)(ws + off); off += (size_t)8 * NV * 4;
  float* region = (float*)(ws + off);
  float* wh = region;      // dead after k_tr
  float* out_p = region;   // S slabs of [NV][MOUT] f32

  int S = 8;
  while (S > 1 && off + (size_t)S * NV * MOUT * 4 > ws_size) S >>= 1;

  k_wh<<<NV / 32, 256, 0, stream>>>(h, w, a1, a2, wh, wh1, wh2);
  k_tr<<<NV / 64, 256, 0, stream>>>(wh, fragB);
  k_attn_p<<<dim3(NV / 32, S), 256, 0, stream>>>(fragB, adj, wh1, wh2, out_p, psum_p, 128 / S);
  k_comb<<<(NV * MOUT / 4) / 256, 256, 0, stream>>>(out_p, psum_p, out, S);
}

// Round 6
// 172.935 us; speedup vs baseline: 1.6068x; 1.6068x over previous
//
#include <hip/hip_runtime.h>
#include <hip/hip_bf16.h>
#include <cstdint>
#include <cstddef>

#define NV    8192   // nodes
#define KIN   512    // in features
#define MOUT  128    // out features
#define LOG2E 1.4426950408889634f

typedef __attribute__((ext_vector_type(4))) float f32x4;
typedef __attribute__((ext_vector_type(8))) short short8;

__device__ __forceinline__ unsigned short f2bf(float x) {
  unsigned int u = __float_as_uint(x);
  return (unsigned short)((u + 0x7fffu + ((u >> 16) & 1u)) >> 16);  // RNE
}
__device__ __forceinline__ float elu1(float x) { return x > 0.f ? x : expm1f(x); }

// ---------------- kernel 1: wh = h @ w^T (fp32) + fused wh1/wh2 (log2-scaled) ----------------
__global__ __launch_bounds__(256) void k_wh(const float* __restrict__ h,
                                            const float* __restrict__ w,
                                            const float* __restrict__ a1,
                                            const float* __restrict__ a2,
                                            float* __restrict__ wh,
                                            float* __restrict__ wh1,
                                            float* __restrict__ wh2) {
  __shared__ __align__(16) float hT[64][36];
  __shared__ __align__(16) float wT[64][128];
  const int t = threadIdx.x;
  const int row0 = blockIdx.x * 32;
  const int hr = t >> 3, hu = t & 7;
  const int wc = t >> 1, whalf = t & 1;
  const int cg = t & 31, rg = t >> 5;
  const int c0 = cg * 4, r0 = rg * 4;
  float acc[4][4] = {};

  for (int kt = 0; kt < 8; ++kt) {
    const int k0 = kt * 64;
    __syncthreads();
#pragma unroll
    for (int v = 0; v < 8; ++v)
      hT[hu + 8 * v][hr] = h[(size_t)(row0 + hr) * KIN + k0 + hu + 8 * v];
#pragma unroll
    for (int mv = 0; mv < 8; ++mv) {
      const float4 wv = *(const float4*)&w[(size_t)wc * KIN + k0 + whalf * 32 + mv * 4];
      wT[whalf * 32 + mv * 4 + 0][wc] = wv.x;
      wT[whalf * 32 + mv * 4 + 1][wc] = wv.y;
      wT[whalf * 32 + mv * 4 + 2][wc] = wv.z;
      wT[whalf * 32 + mv * 4 + 3][wc] = wv.w;
    }
    __syncthreads();
#pragma unroll 8
    for (int kk = 0; kk < 64; ++kk) {
      const float4 hv = *(const float4*)&hT[kk][r0];
      const float4 wv = *(const float4*)&wT[kk][c0];
      const float hvv[4] = {hv.x, hv.y, hv.z, hv.w};
      const float wvv[4] = {wv.x, wv.y, wv.z, wv.w};
#pragma unroll
      for (int i = 0; i < 4; ++i)
#pragma unroll
        for (int j = 0; j < 4; ++j)
          acc[i][j] = fmaf(hvv[i], wvv[j], acc[i][j]);
    }
  }

  const float4 a1v = *(const float4*)&a1[c0];
  const float4 a2v = *(const float4*)&a2[c0];
#pragma unroll
  for (int i = 0; i < 4; ++i) {
    float4 o;
    o.x = acc[i][0]; o.y = acc[i][1]; o.z = acc[i][2]; o.w = acc[i][3];
    *(float4*)&wh[(size_t)(row0 + r0 + i) * MOUT + c0] = o;
    float s1 = acc[i][0] * a1v.x + acc[i][1] * a1v.y + acc[i][2] * a1v.z + acc[i][3] * a1v.w;
    float s2 = acc[i][0] * a2v.x + acc[i][1] * a2v.y + acc[i][2] * a2v.z + acc[i][3] * a2v.w;
#pragma unroll
    for (int off = 16; off > 0; off >>= 1) {
      s1 += __shfl_down(s1, off, 32);
      s2 += __shfl_down(s2, off, 32);
    }
    if (cg == 0) {
      wh1[row0 + r0 + i] = s1 * LOG2E;   // log2-domain scores
      wh2[row0 + r0 + i] = s2 * LOG2E;
    }
  }
}

// ---------------- kernel 2: fragB = bf16(wh) in MFMA-fragment order ----------------
// fragB[jt][cg][ks][lane][e] = bf16(wh[jt*64 + ks*32 + (lane>>4)*8 + e][cg*16 + (lane&15)])
__global__ __launch_bounds__(256) void k_tr(const float* __restrict__ wh,
                                            unsigned short* __restrict__ fragB) {
  __shared__ __align__(16) unsigned short ldsT[128][72];
  const int t = threadIdx.x;
  const int j0 = blockIdx.x * 64;
  {
    const int jr = t >> 2, q = t & 3;
#pragma unroll
    for (int mv = 0; mv < 8; ++mv) {
      const float4 v = *(const float4*)&wh[(size_t)(j0 + jr) * MOUT + q * 32 + mv * 4];
      ldsT[q * 32 + mv * 4 + 0][jr] = f2bf(v.x);
      ldsT[q * 32 + mv * 4 + 1][jr] = f2bf(v.y);
      ldsT[q * 32 + mv * 4 + 2][jr] = f2bf(v.z);
      ldsT[q * 32 + mv * 4 + 3][jr] = f2bf(v.w);
    }
  }
  __syncthreads();
  {
#pragma unroll
    for (int k = 0; k < 4; ++k) {
      const int K = k * 256 + t;
      const int cg = K >> 7, ks = (K >> 6) & 1, ln = K & 63;
      const int lg = ln >> 4, l15 = ln & 15;
      const short8 v = *(const short8*)&ldsT[cg * 16 + l15][ks * 32 + lg * 8];
      *(short8*)&fragB[((size_t)blockIdx.x * 1024 + K) * 8] = v;
    }
  }
}

// ---------------- kernel 3: barrier-free partial attention + PV (bf16 MFMA) ----------------
// grid (256, S) x 256 thr. Wave wv=(ih,ch): 16 i-rows x 64 c-cols.
// P fragment in registers (log2-domain, exp2), B fragments streamed from L2. No LDS.
// NOTE: launch_bounds min-waves kept at 4: demanding 8 forces a 32-VGPR squeeze
// and ~180 MB of scratch spill traffic (round-5 regression). 64 VGPR already
// allows 8 waves/SIMD; the S=8 grid (2048 blocks = 8 blocks/CU) supplies them.
__global__ __launch_bounds__(256, 4) void k_attn_p(const unsigned short* __restrict__ fragB,
                                                   const int* __restrict__ adj,
                                                   const float* __restrict__ wh1l,
                                                   const float* __restrict__ wh2l,
                                                   float* __restrict__ out_p,
                                                   float* __restrict__ psum_p,
                                                   int ntiles) {
  const int t = threadIdx.x;
  const int i0 = blockIdx.x * 32;
  const int jbase = blockIdx.y * ntiles * 64;
  const int lane = t & 63;
  const int wv = t >> 6;
  const int ih = wv & 1, ch = wv >> 1;
  const int l15 = lane & 15, lg = lane >> 4;

  const int row = i0 + ih * 16 + l15;
  const float wh1r = wh1l[row];
  const int* aptr = adj + (size_t)row * NV + jbase + lg * 8;
  const unsigned short* bptr = fragB + (size_t)(jbase >> 6) * 8192 + ch * 4096 + lane * 8;
  const float* w2ptr = wh2l + jbase + lg * 8;

  f32x4 acc[4] = {};
  float psum = 0.f;

  // prologue: adj prefetch for tile 0
  int4 a0 = *(const int4*)(aptr);
  int4 a1 = *(const int4*)(aptr + 4);
  int4 a2 = *(const int4*)(aptr + 32);
  int4 a3 = *(const int4*)(aptr + 36);
  aptr += 64;

  for (int it = 0; it < ntiles; ++it) {
    // adj values are {0,1}: bit0 == (a>0)
    const unsigned int m =
        (unsigned)(a0.x & 1)        | ((unsigned)(a0.y & 1) << 1)  |
        ((unsigned)(a0.z & 1) << 2) | ((unsigned)(a0.w & 1) << 3)  |
        ((unsigned)(a1.x & 1) << 4) | ((unsigned)(a1.y & 1) << 5)  |
        ((unsigned)(a1.z & 1) << 6) | ((unsigned)(a1.w & 1) << 7)  |
        ((unsigned)(a2.x & 1) << 8) | ((unsigned)(a2.y & 1) << 9)  |
        ((unsigned)(a2.z & 1) << 10)| ((unsigned)(a2.w & 1) << 11) |
        ((unsigned)(a3.x & 1) << 12)| ((unsigned)(a3.y & 1) << 13) |
        ((unsigned)(a3.z & 1) << 14)| ((unsigned)(a3.w & 1) << 15);
    // prefetch next tile's adj (HBM latency hidden across the iteration + TLP)
    if (it + 1 < ntiles) {
      a0 = *(const int4*)(aptr);
      a1 = *(const int4*)(aptr + 4);
      a2 = *(const int4*)(aptr + 32);
      a3 = *(const int4*)(aptr + 36);
      aptr += 64;
    }
#pragma unroll
    for (int ks = 0; ks < 2; ++ks) {
      const short8 bf0 = *(const short8*)(bptr + ks * 512);
      const short8 bf1 = *(const short8*)(bptr + 1024 + ks * 512);
      const short8 bf2 = *(const short8*)(bptr + 2048 + ks * 512);
      const short8 bf3 = *(const short8*)(bptr + 3072 + ks * 512);
      const float4 wa = *(const float4*)(w2ptr + ks * 32);
      const float4 wb = *(const float4*)(w2ptr + ks * 32 + 4);
      const float w2v[8] = {wa.x, wa.y, wa.z, wa.w, wb.x, wb.y, wb.z, wb.w};
      union { short8 s8; __hip_bfloat162 h2[4]; } pk;
#pragma unroll
      for (int e = 0; e < 4; ++e) {   // pairs: short pe live range
        const float x0 = wh1r + w2v[2 * e];
        const float x1 = wh1r + w2v[2 * e + 1];
        const float l0 = fmaxf(x0, 0.01f * x0);
        const float l1 = fmaxf(x1, 0.01f * x1);
        float p0 = __builtin_amdgcn_exp2f(l0);
        float p1 = __builtin_amdgcn_exp2f(l1);
        p0 = ((m >> (ks * 8 + 2 * e)) & 1u) ? p0 : 0.f;
        p1 = ((m >> (ks * 8 + 2 * e + 1)) & 1u) ? p1 : 0.f;
        psum += p0 + p1;
        pk.h2[e] = __float22bfloat162_rn(make_float2(p0, p1));
      }
      const short8 af = pk.s8;
      acc[0] = __builtin_amdgcn_mfma_f32_16x16x32_bf16(af, bf0, acc[0], 0, 0, 0);
      acc[1] = __builtin_amdgcn_mfma_f32_16x16x32_bf16(af, bf1, acc[1], 0, 0, 0);
      acc[2] = __builtin_amdgcn_mfma_f32_16x16x32_bf16(af, bf2, acc[2], 0, 0, 0);
      acc[3] = __builtin_amdgcn_mfma_f32_16x16x32_bf16(af, bf3, acc[3], 0, 0, 0);
    }
    bptr += 8192;
    w2ptr += 64;
  }

  // partial row sums (lanes 16 apart share l15; ch halves both computed full rows)
  psum += __shfl_xor(psum, 16, 64);
  psum += __shfl_xor(psum, 32, 64);
  if (ch == 0 && lg == 0)
    psum_p[(size_t)blockIdx.y * NV + row] = psum;

  // store unnormalized partial tile (C/D: col=l15, row=lg*4+r)
  const size_t ob = ((size_t)blockIdx.y * NV + i0 + ih * 16) * MOUT + ch * 64;
#pragma unroll
  for (int cgl = 0; cgl < 4; ++cgl)
#pragma unroll
    for (int r = 0; r < 4; ++r)
      out_p[ob + (size_t)(lg * 4 + r) * MOUT + cgl * 16 + l15] = acc[cgl][r];
}

// ---------------- kernel 4: combine partials, normalize, ELU ----------------
__global__ __launch_bounds__(256) void k_comb(const float* __restrict__ out_p,
                                              const float* __restrict__ psum_p,
                                              float* __restrict__ out, int S) {
  const int idx = (blockIdx.x * 256 + threadIdx.x) * 4;
  const int n = idx >> 7;  // MOUT = 128
  float denom = 0.f;
  for (int s = 0; s < S; ++s) denom += psum_p[(size_t)s * NV + n];
  float4 acc = {0.f, 0.f, 0.f, 0.f};
  for (int s = 0; s < S; ++s) {
    const float4 v = *(const float4*)&out_p[(size_t)s * NV * MOUT + idx];
    acc.x += v.x; acc.y += v.y; acc.z += v.z; acc.w += v.w;
  }
  const float inv = 1.f / denom;
  float4 o;
  o.x = elu1(acc.x * inv);
  o.y = elu1(acc.y * inv);
  o.z = elu1(acc.z * inv);
  o.w = elu1(acc.w * inv);
  *(float4*)&out[idx] = o;
}

extern "C" void kernel_launch(void* const* d_in, const int* in_sizes, int n_in,
                              void* d_out, int out_size, void* d_ws, size_t ws_size,
                              hipStream_t stream) {
  const float* h  = (const float*)d_in[0];
  const int* adj  = (const int*)d_in[1];
  const float* w  = (const float*)d_in[2];
  const float* a1 = (const float*)d_in[3];
  const float* a2 = (const float*)d_in[4];
  float* out = (float*)d_out;

  char* ws = (char*)d_ws;
  // layout: [fragB 2MB][wh1][wh2][psum_p 8*32KB][region: wh 4MB aliased by out_p slabs]
  unsigned short* fragB = (unsigned short*)ws;
  size_t off = (size_t)MOUT * NV * 2;
  float* wh1 = (float*)(ws + off); off += (size_t)NV * 4;
  float* wh2 = (float*)(ws + off); off += (size_t)NV * 4;
  float* psum_p = (float*)(ws + off); off += (size_t)8 * NV * 4;
  float* region = (float*)(ws + off);
  float* wh = region;      // dead after k_tr
  float* out_p = region;   // S slabs of [NV][MOUT] f32

  int S = 8;
  while (S > 1 && off + (size_t)S * NV * MOUT * 4 > ws_size) S >>= 1;

  k_wh<<<NV / 32, 256, 0, stream>>>(h, w, a1, a2, wh, wh1, wh2);
  k_tr<<<NV / 64, 256, 0, stream>>>(wh, fragB);
  k_attn_p<<<dim3(NV / 32, S), 256, 0, stream>>>(fragB, adj, wh1, wh2, out_p, psum_p, 128 / S);
  k_comb<<<(NV * MOUT / 4) / 256, 256, 0, stream>>>(out_p, psum_p, out, S);
}

// Round 7
// 163.529 us; speedup vs baseline: 1.6992x; 1.0575x over previous
//
#include <hip/hip_runtime.h>
#include <hip/hip_bf16.h>
#include <cstdint>
#include <cstddef>

#define NV    8192   // nodes
#define KIN   512    // in features
#define MOUT  128    // out features
#define LOG2E 1.4426950408889634f

typedef __attribute__((ext_vector_type(4))) float f32x4;
typedef __attribute__((ext_vector_type(8))) short short8;

__device__ __forceinline__ unsigned short f2bf(float x) {
  unsigned int u = __float_as_uint(x);
  return (unsigned short)((u + 0x7fffu + ((u >> 16) & 1u)) >> 16);  // RNE
}
__device__ __forceinline__ float elu1(float x) { return x > 0.f ? x : expm1f(x); }

// ---------------- kernel 1 (fused): blocks 0-255: wh = h@w^T + wh1/wh2(log2)
//                                    blocks 256-1279: adj -> bit-mask (fragment-ordered)
// Pack layout: maskw ushort at ((row*128 + jt)*4 + lg); bit (ks*8+e) = adj[row][jt*64+ks*32+lg*8+e].
// Pack reads are SEQUENTIAL per wave-row (8k chip streams, DRAM-friendly) — the round-6
// lesson: 16-parallel-row reads in the attn loop caused ~53k streams and ~8k-cycle stalls.
__global__ __launch_bounds__(256, 4) void k_whpack(const float* __restrict__ h,
                                                   const float* __restrict__ w,
                                                   const float* __restrict__ a1,
                                                   const float* __restrict__ a2,
                                                   const int* __restrict__ adj,
                                                   float* __restrict__ wh,
                                                   float* __restrict__ wh1,
                                                   float* __restrict__ wh2,
                                                   unsigned short* __restrict__ maskw) {
  __shared__ __align__(16) float hT[64][36];
  __shared__ __align__(16) float wT[64][128];
  const int t = threadIdx.x;

  if (blockIdx.x >= 256) {
    // ---- pack part: 1024 blocks x 8 rows; wave w owns rows pb*8+w*2+{0,1} sequentially ----
    const int pb = blockIdx.x - 256;
    const int wv = t >> 6, l = t & 63;
#pragma unroll
    for (int rr = 0; rr < 2; ++rr) {
      const int row = pb * 8 + wv * 2 + rr;
      const int* ap = adj + (size_t)row * NV;
      uint2* mp = (uint2*)(maskw + (size_t)row * 512);
#pragma unroll
      for (int half = 0; half < 2; ++half) {
        const int jt = half * 64 + l;
        const int* bp = ap + jt * 64;
        unsigned int m0 = 0, m1 = 0;
#pragma unroll
        for (int p = 0; p < 8; ++p) {
          const int4 v = *(const int4*)&bp[p * 4];
          m0 |= ((unsigned)(v.x & 1) << (4 * p))     | ((unsigned)(v.y & 1) << (4 * p + 1)) |
                ((unsigned)(v.z & 1) << (4 * p + 2)) | ((unsigned)(v.w & 1) << (4 * p + 3));
        }
#pragma unroll
        for (int p = 0; p < 8; ++p) {
          const int4 v = *(const int4*)&bp[32 + p * 4];
          m1 |= ((unsigned)(v.x & 1) << (4 * p))     | ((unsigned)(v.y & 1) << (4 * p + 1)) |
                ((unsigned)(v.z & 1) << (4 * p + 2)) | ((unsigned)(v.w & 1) << (4 * p + 3));
        }
        // byte-interleave m0/m1 -> ushort[lg] = m0.byte(lg) | m1.byte(lg)<<8
        uint2 o;
        o.x = (m0 & 0xFFu) | ((m1 & 0xFFu) << 8) |
              (((m0 >> 8) & 0xFFu) << 16) | (((m1 >> 8) & 0xFFu) << 24);
        o.y = ((m0 >> 16) & 0xFFu) | (((m1 >> 16) & 0xFFu) << 8) |
              (((m0 >> 24) & 0xFFu) << 16) | ((m1 >> 24) << 24);
        mp[jt] = o;
      }
    }
    return;
  }

  // ---- wh part: 256 blocks, 32 rows x 128 cols ----
  const int row0 = blockIdx.x * 32;
  const int hr = t >> 3, hu = t & 7;
  const int wc = t >> 1, whalf = t & 1;
  const int cg = t & 31, rg = t >> 5;
  const int c0 = cg * 4, r0 = rg * 4;
  float acc[4][4] = {};

  for (int kt = 0; kt < 8; ++kt) {
    const int k0 = kt * 64;
    __syncthreads();
#pragma unroll
    for (int v = 0; v < 8; ++v)
      hT[hu + 8 * v][hr] = h[(size_t)(row0 + hr) * KIN + k0 + hu + 8 * v];
#pragma unroll
    for (int mv = 0; mv < 8; ++mv) {
      const float4 wv4 = *(const float4*)&w[(size_t)wc * KIN + k0 + whalf * 32 + mv * 4];
      wT[whalf * 32 + mv * 4 + 0][wc] = wv4.x;
      wT[whalf * 32 + mv * 4 + 1][wc] = wv4.y;
      wT[whalf * 32 + mv * 4 + 2][wc] = wv4.z;
      wT[whalf * 32 + mv * 4 + 3][wc] = wv4.w;
    }
    __syncthreads();
#pragma unroll 8
    for (int kk = 0; kk < 64; ++kk) {
      const float4 hv = *(const float4*)&hT[kk][r0];
      const float4 wv4 = *(const float4*)&wT[kk][c0];
      const float hvv[4] = {hv.x, hv.y, hv.z, hv.w};
      const float wvv[4] = {wv4.x, wv4.y, wv4.z, wv4.w};
#pragma unroll
      for (int i = 0; i < 4; ++i)
#pragma unroll
        for (int j = 0; j < 4; ++j)
          acc[i][j] = fmaf(hvv[i], wvv[j], acc[i][j]);
    }
  }

  const float4 a1v = *(const float4*)&a1[c0];
  const float4 a2v = *(const float4*)&a2[c0];
#pragma unroll
  for (int i = 0; i < 4; ++i) {
    float4 o;
    o.x = acc[i][0]; o.y = acc[i][1]; o.z = acc[i][2]; o.w = acc[i][3];
    *(float4*)&wh[(size_t)(row0 + r0 + i) * MOUT + c0] = o;
    float s1 = acc[i][0] * a1v.x + acc[i][1] * a1v.y + acc[i][2] * a1v.z + acc[i][3] * a1v.w;
    float s2 = acc[i][0] * a2v.x + acc[i][1] * a2v.y + acc[i][2] * a2v.z + acc[i][3] * a2v.w;
#pragma unroll
    for (int off = 16; off > 0; off >>= 1) {
      s1 += __shfl_down(s1, off, 32);
      s2 += __shfl_down(s2, off, 32);
    }
    if (cg == 0) {
      wh1[row0 + r0 + i] = s1 * LOG2E;   // log2-domain scores
      wh2[row0 + r0 + i] = s2 * LOG2E;
    }
  }
}

// ---------------- kernel 2: fragB = bf16(wh) in MFMA-fragment order ----------------
__global__ __launch_bounds__(256) void k_tr(const float* __restrict__ wh,
                                            unsigned short* __restrict__ fragB) {
  __shared__ __align__(16) unsigned short ldsT[128][72];
  const int t = threadIdx.x;
  const int j0 = blockIdx.x * 64;
  {
    const int jr = t >> 2, q = t & 3;
#pragma unroll
    for (int mv = 0; mv < 8; ++mv) {
      const float4 v = *(const float4*)&wh[(size_t)(j0 + jr) * MOUT + q * 32 + mv * 4];
      ldsT[q * 32 + mv * 4 + 0][jr] = f2bf(v.x);
      ldsT[q * 32 + mv * 4 + 1][jr] = f2bf(v.y);
      ldsT[q * 32 + mv * 4 + 2][jr] = f2bf(v.z);
      ldsT[q * 32 + mv * 4 + 3][jr] = f2bf(v.w);
    }
  }
  __syncthreads();
  {
#pragma unroll
    for (int k = 0; k < 4; ++k) {
      const int K = k * 256 + t;
      const int cg = K >> 7, ks = (K >> 6) & 1, ln = K & 63;
      const int lg = ln >> 4, l15 = ln & 15;
      const short8 v = *(const short8*)&ldsT[cg * 16 + l15][ks * 32 + lg * 8];
      *(short8*)&fragB[((size_t)blockIdx.x * 1024 + K) * 8] = v;
    }
  }
}

// ---------------- kernel 3: attention partials — L2-only main loop, no barriers ----------------
// grid (256, S) x 256 thr. Wave wv=(ih,ch): 16 i-rows x 64 c-cols. Main loop reads:
// mask ushort (L2/L3) + 8 B-fragments (L2) + wh2 (L1/L2). psum comes free via a
// ones-column MFMA (B = bf16 1.0 fragment) — no per-iter VALU adds, no shuffles.
__global__ __launch_bounds__(256, 4) void k_attn_p(const unsigned short* __restrict__ fragB,
                                                   const unsigned short* __restrict__ maskw,
                                                   const float* __restrict__ wh1l,
                                                   const float* __restrict__ wh2l,
                                                   float* __restrict__ out_p,
                                                   float* __restrict__ psum_p,
                                                   int ntiles) {
  const int t = threadIdx.x;
  const int i0 = blockIdx.x * 32;
  const int jbase = blockIdx.y * ntiles * 64;
  const int lane = t & 63;
  const int wv = t >> 6;
  const int ih = wv & 1, ch = wv >> 1;
  const int l15 = lane & 15, lg = lane >> 4;

  const int row = i0 + ih * 16 + l15;
  const float wh1r = wh1l[row];
  const unsigned short* mptr = maskw + ((size_t)row * 128 + (jbase >> 6)) * 4 + lg;
  const unsigned short* bptr = fragB + (size_t)(jbase >> 6) * 8192 + ch * 4096 + lane * 8;
  const float* w2ptr = wh2l + jbase + lg * 8;

  f32x4 acc[4] = {};
  f32x4 accs = {};
  short8 onesf;
#pragma unroll
  for (int e = 0; e < 8; ++e) onesf[e] = (short)0x3F80;  // bf16 1.0

  // single-set per-tile state; next-tile loads issue after last use (compiler WAR order)
  unsigned int m16 = *mptr; mptr += 4;
  float4 wq0 = *(const float4*)(w2ptr);
  float4 wq1 = *(const float4*)(w2ptr + 4);
  float4 wq2 = *(const float4*)(w2ptr + 32);
  float4 wq3 = *(const float4*)(w2ptr + 36);
  w2ptr += 64;
  short8 bf[8];
#pragma unroll
  for (int ks = 0; ks < 2; ++ks)
#pragma unroll
    for (int cgl = 0; cgl < 4; ++cgl)
      bf[ks * 4 + cgl] = *(const short8*)(bptr + cgl * 1024 + ks * 512);
  bptr += 8192;

  for (int it = 0; it < ntiles; ++it) {
    // ---- P compute (log2-domain, exp2) -> A fragments ----
    short8 af[2];
#pragma unroll
    for (int ks = 0; ks < 2; ++ks) {
      const float4 wa = ks ? wq2 : wq0;
      const float4 wb = ks ? wq3 : wq1;
      const float w2v[8] = {wa.x, wa.y, wa.z, wa.w, wb.x, wb.y, wb.z, wb.w};
      union { short8 s8; __hip_bfloat162 h2[4]; } pk;
#pragma unroll
      for (int e = 0; e < 4; ++e) {
        const float x0 = wh1r + w2v[2 * e];
        const float x1 = wh1r + w2v[2 * e + 1];
        const float l0 = fmaxf(x0, 0.01f * x0);
        const float l1 = fmaxf(x1, 0.01f * x1);
        float p0 = __builtin_amdgcn_exp2f(l0);
        float p1 = __builtin_amdgcn_exp2f(l1);
        p0 = ((m16 >> (ks * 8 + 2 * e)) & 1u) ? p0 : 0.f;
        p1 = ((m16 >> (ks * 8 + 2 * e + 1)) & 1u) ? p1 : 0.f;
        pk.h2[e] = __float22bfloat162_rn(make_float2(p0, p1));
      }
      af[ks] = pk.s8;
    }
    // ---- prefetch next tile's mask + w2 (last use above) ----
    if (it + 1 < ntiles) {
      m16 = *mptr; mptr += 4;
      wq0 = *(const float4*)(w2ptr);
      wq1 = *(const float4*)(w2ptr + 4);
      wq2 = *(const float4*)(w2ptr + 32);
      wq3 = *(const float4*)(w2ptr + 36);
      w2ptr += 64;
    }
    // ---- MFMA accumulate (incl. ones-column row-sum) ----
    acc[0] = __builtin_amdgcn_mfma_f32_16x16x32_bf16(af[0], bf[0], acc[0], 0, 0, 0);
    acc[1] = __builtin_amdgcn_mfma_f32_16x16x32_bf16(af[0], bf[1], acc[1], 0, 0, 0);
    acc[2] = __builtin_amdgcn_mfma_f32_16x16x32_bf16(af[0], bf[2], acc[2], 0, 0, 0);
    acc[3] = __builtin_amdgcn_mfma_f32_16x16x32_bf16(af[0], bf[3], acc[3], 0, 0, 0);
    accs   = __builtin_amdgcn_mfma_f32_16x16x32_bf16(af[0], onesf, accs, 0, 0, 0);
    acc[0] = __builtin_amdgcn_mfma_f32_16x16x32_bf16(af[1], bf[4], acc[0], 0, 0, 0);
    acc[1] = __builtin_amdgcn_mfma_f32_16x16x32_bf16(af[1], bf[5], acc[1], 0, 0, 0);
    acc[2] = __builtin_amdgcn_mfma_f32_16x16x32_bf16(af[1], bf[6], acc[2], 0, 0, 0);
    acc[3] = __builtin_amdgcn_mfma_f32_16x16x32_bf16(af[1], bf[7], acc[3], 0, 0, 0);
    accs   = __builtin_amdgcn_mfma_f32_16x16x32_bf16(af[1], onesf, accs, 0, 0, 0);
    // ---- prefetch next tile's B fragments (consumed just above) ----
    if (it + 1 < ntiles) {
#pragma unroll
      for (int ks = 0; ks < 2; ++ks)
#pragma unroll
        for (int cgl = 0; cgl < 4; ++cgl)
          bf[ks * 4 + cgl] = *(const short8*)(bptr + cgl * 1024 + ks * 512);
      bptr += 8192;
    }
  }

  // psum: accs col c is identical for all c; lane(l15,lg) reg r holds rowsum[lg*4+r]
  if (ch == 0 && l15 == 0) {
#pragma unroll
    for (int r = 0; r < 4; ++r)
      psum_p[(size_t)blockIdx.y * NV + i0 + ih * 16 + lg * 4 + r] = accs[r];
  }

  // store unnormalized partial tile (C/D: col=l15, row=lg*4+r)
  const size_t ob = ((size_t)blockIdx.y * NV + i0 + ih * 16) * MOUT + ch * 64;
#pragma unroll
  for (int cgl = 0; cgl < 4; ++cgl)
#pragma unroll
    for (int r = 0; r < 4; ++r)
      out_p[ob + (size_t)(lg * 4 + r) * MOUT + cgl * 16 + l15] = acc[cgl][r];
}

// ---------------- kernel 4: combine partials, normalize, ELU ----------------
__global__ __launch_bounds__(256) void k_comb(const float* __restrict__ out_p,
                                              const float* __restrict__ psum_p,
                                              float* __restrict__ out, int S) {
  const int idx = (blockIdx.x * 256 + threadIdx.x) * 4;
  const int n = idx >> 7;  // MOUT = 128
  float denom = 0.f;
  for (int s = 0; s < S; ++s) denom += psum_p[(size_t)s * NV + n];
  float4 acc = {0.f, 0.f, 0.f, 0.f};
  for (int s = 0; s < S; ++s) {
    const float4 v = *(const float4*)&out_p[(size_t)s * NV * MOUT + idx];
    acc.x += v.x; acc.y += v.y; acc.z += v.z; acc.w += v.w;
  }
  const float inv = 1.f / denom;
  float4 o;
  o.x = elu1(acc.x * inv);
  o.y = elu1(acc.y * inv);
  o.z = elu1(acc.z * inv);
  o.w = elu1(acc.w * inv);
  *(float4*)&out[idx] = o;
}

extern "C" void kernel_launch(void* const* d_in, const int* in_sizes, int n_in,
                              void* d_out, int out_size, void* d_ws, size_t ws_size,
                              hipStream_t stream) {
  const float* h  = (const float*)d_in[0];
  const int* adj  = (const int*)d_in[1];
  const float* w  = (const float*)d_in[2];
  const float* a1 = (const float*)d_in[3];
  const float* a2 = (const float*)d_in[4];
  float* out = (float*)d_out;

  char* ws = (char*)d_ws;
  // layout: [fragB 2MB][wh1][wh2][psum_p 256KB][maskw 8MB][region: wh 4MB aliased by out_p]
  unsigned short* fragB = (unsigned short*)ws;
  size_t off = (size_t)MOUT * NV * 2;
  float* wh1 = (float*)(ws + off); off += (size_t)NV * 4;
  float* wh2 = (float*)(ws + off); off += (size_t)NV * 4;
  float* psum_p = (float*)(ws + off); off += (size_t)8 * NV * 4;
  unsigned short* maskw = (unsigned short*)(ws + off); off += (size_t)NV * 512 * 2;
  float* region = (float*)(ws + off);
  float* wh = region;      // dead after k_tr
  float* out_p = region;   // S slabs of [NV][MOUT] f32

  int S = 8;
  while (S > 1 && off + (size_t)S * NV * MOUT * 4 > ws_size) S >>= 1;

  k_whpack<<<256 + 1024, 256, 0, stream>>>(h, w, a1, a2, adj, wh, wh1, wh2, maskw);
  k_tr<<<NV / 64, 256, 0, stream>>>(wh, fragB);
  k_attn_p<<<dim3(NV / 32, S), 256, 0, stream>>>(fragB, maskw, wh1, wh2, out_p, psum_p, 128 / S);
  k_comb<<<(NV * MOUT / 4) / 256, 256, 0, stream>>>(out_p, psum_p, out, S);
}

// Round 8
// 141.650 us; speedup vs baseline: 1.9617x; 1.1545x over previous
//
#include <hip/hip_runtime.h>
#include <hip/hip_bf16.h>
#include <cstdint>
#include <cstddef>

#define NV    8192   // nodes
#define KIN   512    // in features
#define MOUT  128    // out features
#define LOG2E 1.4426950408889634f

typedef __attribute__((ext_vector_type(4))) float f32x4;
typedef __attribute__((ext_vector_type(8))) short short8;

__device__ __forceinline__ float elu1(float x) { return x > 0.f ? x : expm1f(x); }

__device__ __forceinline__ unsigned int pkbf2(float a, float b) {
  union { __hip_bfloat162 h2; unsigned int u; } r;
  r.h2 = __float22bfloat162_rn(make_float2(a, b));
  return r.u;
}

// ---------------- kernel 1: wh1/wh2 (log2-scaled) + fragB (bf16, MFMA-fragment order) ----------------
// fragB[jt][cg][ks][lane][e] = bf16(wh[jt*64+ks*32+(lane>>4)*8+e][cg*16+(lane&15)])
// Block owns rows row0..row0+31 => jt=row0>>6, ks=(row0>>5)&1 are block constants;
// fragB is emitted straight from the GEMM accumulators (no f32 wh buffer, no k_tr pass).
__global__ __launch_bounds__(256) void k_wh(const float* __restrict__ h,
                                            const float* __restrict__ w,
                                            const float* __restrict__ a1,
                                            const float* __restrict__ a2,
                                            unsigned short* __restrict__ fragB,
                                            float* __restrict__ wh1,
                                            float* __restrict__ wh2) {
  __shared__ __align__(16) float hT[64][36];
  __shared__ __align__(16) float wT[64][128];
  const int t = threadIdx.x;
  const int row0 = blockIdx.x * 32;
  const int hr = t >> 3, hu = t & 7;
  const int wc = t >> 1, whalf = t & 1;
  const int cg = t & 31, rg = t >> 5;
  const int c0 = cg * 4, r0 = rg * 4;
  float acc[4][4] = {};

  for (int kt = 0; kt < 8; ++kt) {
    const int k0 = kt * 64;
    __syncthreads();
#pragma unroll
    for (int v = 0; v < 8; ++v)
      hT[hu + 8 * v][hr] = h[(size_t)(row0 + hr) * KIN + k0 + hu + 8 * v];
#pragma unroll
    for (int mv = 0; mv < 8; ++mv) {
      const float4 wv4 = *(const float4*)&w[(size_t)wc * KIN + k0 + whalf * 32 + mv * 4];
      wT[whalf * 32 + mv * 4 + 0][wc] = wv4.x;
      wT[whalf * 32 + mv * 4 + 1][wc] = wv4.y;
      wT[whalf * 32 + mv * 4 + 2][wc] = wv4.z;
      wT[whalf * 32 + mv * 4 + 3][wc] = wv4.w;
    }
    __syncthreads();
#pragma unroll 8
    for (int kk = 0; kk < 64; ++kk) {
      const float4 hv = *(const float4*)&hT[kk][r0];
      const float4 wv4 = *(const float4*)&wT[kk][c0];
      const float hvv[4] = {hv.x, hv.y, hv.z, hv.w};
      const float wvv[4] = {wv4.x, wv4.y, wv4.z, wv4.w};
#pragma unroll
      for (int i = 0; i < 4; ++i)
#pragma unroll
        for (int j = 0; j < 4; ++j)
          acc[i][j] = fmaf(hvv[i], wvv[j], acc[i][j]);
    }
  }

  // ---- fragB store: rows rg*4+i -> (lg = rg>>1, e = (rg&1)*4+i); cols cg*4+j -> (cgf=cg>>2, l15=(cg&3)*4+j)
  {
    const size_t jt = (size_t)(row0 >> 6);
    const int ks = (row0 >> 5) & 1;
    const int lg = rg >> 1, ebase = (rg & 1) * 4;
    const int cgf = cg >> 2;
    const size_t fbase = (((jt * 8 + cgf) * 2 + ks) * 64 + lg * 16) * 8 + ebase;
#pragma unroll
    for (int j = 0; j < 4; ++j) {
      const int l15 = (cg & 3) * 4 + j;
      uint2 o;
      o.x = pkbf2(acc[0][j], acc[1][j]);
      o.y = pkbf2(acc[2][j], acc[3][j]);
      *(uint2*)&fragB[fbase + (size_t)l15 * 8] = o;
    }
  }

  // ---- wh1/wh2 fused reductions (log2 domain) ----
  const float4 a1v = *(const float4*)&a1[c0];
  const float4 a2v = *(const float4*)&a2[c0];
#pragma unroll
  for (int i = 0; i < 4; ++i) {
    float s1 = acc[i][0] * a1v.x + acc[i][1] * a1v.y + acc[i][2] * a1v.z + acc[i][3] * a1v.w;
    float s2 = acc[i][0] * a2v.x + acc[i][1] * a2v.y + acc[i][2] * a2v.z + acc[i][3] * a2v.w;
#pragma unroll
    for (int off = 16; off > 0; off >>= 1) {
      s1 += __shfl_down(s1, off, 32);
      s2 += __shfl_down(s2, off, 32);
    }
    if (cg == 0) {
      wh1[row0 + r0 + i] = s1 * LOG2E;
      wh2[row0 + r0 + i] = s2 * LOG2E;
    }
  }
}

// ---------------- kernel 2: fused adj-pack + attention partials ----------------
// grid (256, S) x 256. Phase 0: block packs its own 32-row x (ntiles*64)-col adj slice
// into an LDS bitmask via DENSE per-row bursts (4 KB/row, 4x int4 per lane) — the
// round-6 lesson: fine-grained interleaved adj reads thrash DRAM; burst them.
// Phase 1: L2-only tile loop (mask ds_read_b64 broadcast + fragB + wh2), ones-column
// MFMA row-sums, no per-tile barriers.
__global__ __launch_bounds__(256, 4) void k_attn_p(const unsigned short* __restrict__ fragB,
                                                   const int* __restrict__ adj,
                                                   const float* __restrict__ wh1l,
                                                   const float* __restrict__ wh2l,
                                                   float* __restrict__ out_p,
                                                   float* __restrict__ psum_p,
                                                   int ntiles) {
  extern __shared__ char smem[];          // 32 rows x (ntiles*8 + 8) bytes
  const int t = threadIdx.x;
  const int i0 = blockIdx.x * 32;
  const int jbase = blockIdx.y * ntiles * 64;
  const int lane = t & 63, wv = t >> 6;
  const int ih = wv & 1, ch = wv >> 1;
  const int l15 = lane & 15, lg = lane >> 4;
  const int mstride = ntiles * 8 + 8;     // dword stride % 32 == 2 -> conflict-free reads

  // ---- phase 0: pack adj slice -> LDS bitmask ----
  {
    const int nchunk = ntiles >> 4;       // 64-lane chunk groups per row (>=1 since S<=8)
    for (int rr = 0; rr < 8; ++rr) {
      const int r = wv * 8 + rr;          // wave owns 8 rows
      const int* ap = adj + (size_t)(i0 + r) * NV + jbase;
      for (int c = 0; c < nchunk; ++c) {
        const int chunk = c * 64 + lane;  // 16 consecutive j's per chunk
        const int* bp = ap + chunk * 16;
        const int4 v0 = *(const int4*)(bp);
        const int4 v1 = *(const int4*)(bp + 4);
        const int4 v2 = *(const int4*)(bp + 8);
        const int4 v3 = *(const int4*)(bp + 12);
        const unsigned int m =
            (unsigned)(v0.x & 1)        | ((unsigned)(v0.y & 1) << 1)  |
            ((unsigned)(v0.z & 1) << 2) | ((unsigned)(v0.w & 1) << 3)  |
            ((unsigned)(v1.x & 1) << 4) | ((unsigned)(v1.y & 1) << 5)  |
            ((unsigned)(v1.z & 1) << 6) | ((unsigned)(v1.w & 1) << 7)  |
            ((unsigned)(v2.x & 1) << 8) | ((unsigned)(v2.y & 1) << 9)  |
            ((unsigned)(v2.z & 1) << 10)| ((unsigned)(v2.w & 1) << 11) |
            ((unsigned)(v3.x & 1) << 12)| ((unsigned)(v3.y & 1) << 13) |
            ((unsigned)(v3.z & 1) << 14)| ((unsigned)(v3.w & 1) << 15);
        *(unsigned short*)&smem[r * mstride + chunk * 2] = (unsigned short)m;
      }
    }
  }
  __syncthreads();

  // ---- phase 1: tile loop ----
  const int row = i0 + ih * 16 + l15;
  const float wh1r = wh1l[row];
  const char* mrow = smem + (ih * 16 + l15) * mstride;
  const unsigned short* bptr = fragB + (size_t)(jbase >> 6) * 8192 + ch * 4096 + lane * 8;
  const float* w2ptr = wh2l + jbase + lg * 8;

  f32x4 acc[4] = {};
  f32x4 accs = {};
  short8 onesf;
#pragma unroll
  for (int e = 0; e < 8; ++e) onesf[e] = (short)0x3F80;  // bf16 1.0

  uint2 m2 = *(const uint2*)&mrow[0];
  float4 wq0 = *(const float4*)(w2ptr);
  float4 wq1 = *(const float4*)(w2ptr + 4);
  float4 wq2 = *(const float4*)(w2ptr + 32);
  float4 wq3 = *(const float4*)(w2ptr + 36);
  w2ptr += 64;
  short8 bf[8];
#pragma unroll
  for (int ks = 0; ks < 2; ++ks)
#pragma unroll
    for (int cgl = 0; cgl < 4; ++cgl)
      bf[ks * 4 + cgl] = *(const short8*)(bptr + cgl * 1024 + ks * 512);
  bptr += 8192;

  for (int it = 0; it < ntiles; ++it) {
    const unsigned int m16 = ((m2.x >> (8 * lg)) & 0xFFu) |
                             (((m2.y >> (8 * lg)) & 0xFFu) << 8);
    short8 af[2];
#pragma unroll
    for (int ks = 0; ks < 2; ++ks) {
      const float4 wa = ks ? wq2 : wq0;
      const float4 wb = ks ? wq3 : wq1;
      const float w2v[8] = {wa.x, wa.y, wa.z, wa.w, wb.x, wb.y, wb.z, wb.w};
      union { short8 s8; __hip_bfloat162 h2[4]; } pk;
#pragma unroll
      for (int e = 0; e < 4; ++e) {
        const float x0 = wh1r + w2v[2 * e];
        const float x1 = wh1r + w2v[2 * e + 1];
        const float l0 = fmaxf(x0, 0.01f * x0);
        const float l1 = fmaxf(x1, 0.01f * x1);
        float p0 = __builtin_amdgcn_exp2f(l0);
        float p1 = __builtin_amdgcn_exp2f(l1);
        p0 = ((m16 >> (ks * 8 + 2 * e)) & 1u) ? p0 : 0.f;
        p1 = ((m16 >> (ks * 8 + 2 * e + 1)) & 1u) ? p1 : 0.f;
        pk.h2[e] = __float22bfloat162_rn(make_float2(p0, p1));
      }
      af[ks] = pk.s8;
    }
    if (it + 1 < ntiles) {
      m2 = *(const uint2*)&mrow[(it + 1) * 8];
      wq0 = *(const float4*)(w2ptr);
      wq1 = *(const float4*)(w2ptr + 4);
      wq2 = *(const float4*)(w2ptr + 32);
      wq3 = *(const float4*)(w2ptr + 36);
      w2ptr += 64;
    }
    acc[0] = __builtin_amdgcn_mfma_f32_16x16x32_bf16(af[0], bf[0], acc[0], 0, 0, 0);
    acc[1] = __builtin_amdgcn_mfma_f32_16x16x32_bf16(af[0], bf[1], acc[1], 0, 0, 0);
    acc[2] = __builtin_amdgcn_mfma_f32_16x16x32_bf16(af[0], bf[2], acc[2], 0, 0, 0);
    acc[3] = __builtin_amdgcn_mfma_f32_16x16x32_bf16(af[0], bf[3], acc[3], 0, 0, 0);
    accs   = __builtin_amdgcn_mfma_f32_16x16x32_bf16(af[0], onesf, accs, 0, 0, 0);
    acc[0] = __builtin_amdgcn_mfma_f32_16x16x32_bf16(af[1], bf[4], acc[0], 0, 0, 0);
    acc[1] = __builtin_amdgcn_mfma_f32_16x16x32_bf16(af[1], bf[5], acc[1], 0, 0, 0);
    acc[2] = __builtin_amdgcn_mfma_f32_16x16x32_bf16(af[1], bf[6], acc[2], 0, 0, 0);
    acc[3] = __builtin_amdgcn_mfma_f32_16x16x32_bf16(af[1], bf[7], acc[3], 0, 0, 0);
    accs   = __builtin_amdgcn_mfma_f32_16x16x32_bf16(af[1], onesf, accs, 0, 0, 0);
    if (it + 1 < ntiles) {
#pragma unroll
      for (int ks = 0; ks < 2; ++ks)
#pragma unroll
        for (int cgl = 0; cgl < 4; ++cgl)
          bf[ks * 4 + cgl] = *(const short8*)(bptr + cgl * 1024 + ks * 512);
      bptr += 8192;
    }
  }

  // psum via ones-column: lane(l15=0,lg) reg r holds rowsum[lg*4+r]
  if (ch == 0 && l15 == 0) {
#pragma unroll
    for (int r = 0; r < 4; ++r)
      psum_p[(size_t)blockIdx.y * NV + i0 + ih * 16 + lg * 4 + r] = accs[r];
  }

  // unnormalized partial tile (C/D: col=l15, row=lg*4+r)
  const size_t ob = ((size_t)blockIdx.y * NV + i0 + ih * 16) * MOUT + ch * 64;
#pragma unroll
  for (int cgl = 0; cgl < 4; ++cgl)
#pragma unroll
    for (int r = 0; r < 4; ++r)
      out_p[ob + (size_t)(lg * 4 + r) * MOUT + cgl * 16 + l15] = acc[cgl][r];
}

// ---------------- kernel 3: combine partials, normalize, ELU ----------------
__global__ __launch_bounds__(256) void k_comb(const float* __restrict__ out_p,
                                              const float* __restrict__ psum_p,
                                              float* __restrict__ out, int S) {
  const int idx = (blockIdx.x * 256 + threadIdx.x) * 4;
  const int n = idx >> 7;  // MOUT = 128
  float denom = 0.f;
  for (int s = 0; s < S; ++s) denom += psum_p[(size_t)s * NV + n];
  float4 acc = {0.f, 0.f, 0.f, 0.f};
  for (int s = 0; s < S; ++s) {
    const float4 v = *(const float4*)&out_p[(size_t)s * NV * MOUT + idx];
    acc.x += v.x; acc.y += v.y; acc.z += v.z; acc.w += v.w;
  }
  const float inv = 1.f / denom;
  float4 o;
  o.x = elu1(acc.x * inv);
  o.y = elu1(acc.y * inv);
  o.z = elu1(acc.z * inv);
  o.w = elu1(acc.w * inv);
  *(float4*)&out[idx] = o;
}

extern "C" void kernel_launch(void* const* d_in, const int* in_sizes, int n_in,
                              void* d_out, int out_size, void* d_ws, size_t ws_size,
                              hipStream_t stream) {
  const float* h  = (const float*)d_in[0];
  const int* adj  = (const int*)d_in[1];
  const float* w  = (const float*)d_in[2];
  const float* a1 = (const float*)d_in[3];
  const float* a2 = (const float*)d_in[4];
  float* out = (float*)d_out;

  char* ws = (char*)d_ws;
  // layout: [fragB 2MB][wh1 32KB][wh2 32KB][psum_p 256KB][out_p S*4MB]
  unsigned short* fragB = (unsigned short*)ws;
  size_t off = (size_t)MOUT * NV * 2;
  float* wh1 = (float*)(ws + off); off += (size_t)NV * 4;
  float* wh2 = (float*)(ws + off); off += (size_t)NV * 4;
  float* psum_p = (float*)(ws + off); off += (size_t)8 * NV * 4;
  float* out_p = (float*)(ws + off);

  int S = 8;
  while (S > 1 && off + (size_t)S * NV * MOUT * 4 > ws_size) S >>= 1;
  const int ntiles = 128 / S;
  const size_t smbytes = (size_t)32 * (ntiles * 8 + 8);

  k_wh<<<NV / 32, 256, 0, stream>>>(h, w, a1, a2, fragB, wh1, wh2);
  k_attn_p<<<dim3(NV / 32, S), 256, smbytes, stream>>>(fragB, adj, wh1, wh2, out_p, psum_p, ntiles);
  k_comb<<<(NV * MOUT / 4) / 256, 256, 0, stream>>>(out_p, psum_p, out, S);
}

// Round 9
// 130.377 us; speedup vs baseline: 2.1313x; 1.0865x over previous
//
#include <hip/hip_runtime.h>
#include <hip/hip_bf16.h>
#include <cstdint>
#include <cstddef>

#define NV    8192   // nodes
#define KIN   512    // in features
#define MOUT  128    // out features
#define LOG2E 1.4426950408889634f

typedef __attribute__((ext_vector_type(4))) float f32x4;
typedef __attribute__((ext_vector_type(8))) short short8;

__device__ __forceinline__ float elu1(float x) { return x > 0.f ? x : expm1f(x); }

__device__ __forceinline__ unsigned int pkbf2(float a, float b) {
  union { __hip_bfloat162 h2; unsigned int u; } r;
  r.h2 = __float22bfloat162_rn(make_float2(a, b));
  return r.u;
}

// ---------------- kernel 1: wh1/wh2 (log2-scaled) + fragB (bf16, MFMA-fragment order) ----------------
// fragB[jt][cg][ks][lane][e] = bf16(wh[jt*64+ks*32+(lane>>4)*8+e][cg*16+(lane&15)])
__global__ __launch_bounds__(256) void k_wh(const float* __restrict__ h,
                                            const float* __restrict__ w,
                                            const float* __restrict__ a1,
                                            const float* __restrict__ a2,
                                            unsigned short* __restrict__ fragB,
                                            float* __restrict__ wh1,
                                            float* __restrict__ wh2) {
  __shared__ __align__(16) float hT[64][36];
  __shared__ __align__(16) float wT[64][128];
  const int t = threadIdx.x;
  const int row0 = blockIdx.x * 32;
  const int hr = t >> 3, hu = t & 7;
  const int wc = t >> 1, whalf = t & 1;
  const int cg = t & 31, rg = t >> 5;
  const int c0 = cg * 4, r0 = rg * 4;
  float acc[4][4] = {};

  for (int kt = 0; kt < 8; ++kt) {
    const int k0 = kt * 64;
    __syncthreads();
#pragma unroll
    for (int v = 0; v < 8; ++v)
      hT[hu + 8 * v][hr] = h[(size_t)(row0 + hr) * KIN + k0 + hu + 8 * v];
#pragma unroll
    for (int mv = 0; mv < 8; ++mv) {
      const float4 wv4 = *(const float4*)&w[(size_t)wc * KIN + k0 + whalf * 32 + mv * 4];
      wT[whalf * 32 + mv * 4 + 0][wc] = wv4.x;
      wT[whalf * 32 + mv * 4 + 1][wc] = wv4.y;
      wT[whalf * 32 + mv * 4 + 2][wc] = wv4.z;
      wT[whalf * 32 + mv * 4 + 3][wc] = wv4.w;
    }
    __syncthreads();
#pragma unroll 8
    for (int kk = 0; kk < 64; ++kk) {
      const float4 hv = *(const float4*)&hT[kk][r0];
      const float4 wv4 = *(const float4*)&wT[kk][c0];
      const float hvv[4] = {hv.x, hv.y, hv.z, hv.w};
      const float wvv[4] = {wv4.x, wv4.y, wv4.z, wv4.w};
#pragma unroll
      for (int i = 0; i < 4; ++i)
#pragma unroll
        for (int j = 0; j < 4; ++j)
          acc[i][j] = fmaf(hvv[i], wvv[j], acc[i][j]);
    }
  }

  // fragB store: rows rg*4+i -> (lg=rg>>1, e=(rg&1)*4+i); cols cg*4+j -> (cgf=cg>>2, l15=(cg&3)*4+j)
  {
    const size_t jt = (size_t)(row0 >> 6);
    const int ks = (row0 >> 5) & 1;
    const int lg = rg >> 1, ebase = (rg & 1) * 4;
    const int cgf = cg >> 2;
    const size_t fbase = (((jt * 8 + cgf) * 2 + ks) * 64 + lg * 16) * 8 + ebase;
#pragma unroll
    for (int j = 0; j < 4; ++j) {
      const int l15 = (cg & 3) * 4 + j;
      uint2 o;
      o.x = pkbf2(acc[0][j], acc[1][j]);
      o.y = pkbf2(acc[2][j], acc[3][j]);
      *(uint2*)&fragB[fbase + (size_t)l15 * 8] = o;
    }
  }

  const float4 a1v = *(const float4*)&a1[c0];
  const float4 a2v = *(const float4*)&a2[c0];
#pragma unroll
  for (int i = 0; i < 4; ++i) {
    float s1 = acc[i][0] * a1v.x + acc[i][1] * a1v.y + acc[i][2] * a1v.z + acc[i][3] * a1v.w;
    float s2 = acc[i][0] * a2v.x + acc[i][1] * a2v.y + acc[i][2] * a2v.z + acc[i][3] * a2v.w;
#pragma unroll
    for (int off = 16; off > 0; off >>= 1) {
      s1 += __shfl_down(s1, off, 32);
      s2 += __shfl_down(s2, off, 32);
    }
    if (cg == 0) {
      wh1[row0 + r0 + i] = s1 * LOG2E;
      wh2[row0 + r0 + i] = s2 * LOG2E;
    }
  }
}

// ---------------- kernel 2: fused adj-pack + attention partials (64-row blocks) ----------------
// grid (128, S) x 256. Phase 0: pack 64-row x (ntiles*64)-col adj slice into LDS bitmask
// via dense per-row bursts. Phase 1: L2-only tile loop; each wave = 32 rows x 64 cols
// (2 A-fragments per B fragment -> fragB L2 traffic halved vs 16-row waves).
__global__ __launch_bounds__(256, 4) void k_attn_p(const unsigned short* __restrict__ fragB,
                                                   const int* __restrict__ adj,
                                                   const float* __restrict__ wh1l,
                                                   const float* __restrict__ wh2l,
                                                   float* __restrict__ out_p,
                                                   float* __restrict__ psum_p,
                                                   int ntiles) {
  extern __shared__ char smem[];          // 64 rows x (ntiles*8 + 8) bytes
  const int t = threadIdx.x;
  const int i0 = blockIdx.x * 64;
  const int jbase = blockIdx.y * ntiles * 64;
  const int lane = t & 63, wv = t >> 6;
  const int ih = wv & 1, ch = wv >> 1;
  const int l15 = lane & 15, lg = lane >> 4;
  const int mstride = ntiles * 8 + 8;

  // ---- phase 0: pack adj slice -> LDS bitmask (wave owns 16 rows, dense 4KB bursts) ----
  {
    const int nchunk = ntiles >> 4;
    for (int rr = 0; rr < 16; ++rr) {
      const int r = wv * 16 + rr;
      const int* ap = adj + (size_t)(i0 + r) * NV + jbase;
      for (int c = 0; c < nchunk; ++c) {
        const int chunk = c * 64 + lane;  // 16 consecutive j's per lane
        const int* bp = ap + chunk * 16;
        const int4 v0 = *(const int4*)(bp);
        const int4 v1 = *(const int4*)(bp + 4);
        const int4 v2 = *(const int4*)(bp + 8);
        const int4 v3 = *(const int4*)(bp + 12);
        const unsigned int m =
            (unsigned)(v0.x & 1)        | ((unsigned)(v0.y & 1) << 1)  |
            ((unsigned)(v0.z & 1) << 2) | ((unsigned)(v0.w & 1) << 3)  |
            ((unsigned)(v1.x & 1) << 4) | ((unsigned)(v1.y & 1) << 5)  |
            ((unsigned)(v1.z & 1) << 6) | ((unsigned)(v1.w & 1) << 7)  |
            ((unsigned)(v2.x & 1) << 8) | ((unsigned)(v2.y & 1) << 9)  |
            ((unsigned)(v2.z & 1) << 10)| ((unsigned)(v2.w & 1) << 11) |
            ((unsigned)(v3.x & 1) << 12)| ((unsigned)(v3.y & 1) << 13) |
            ((unsigned)(v3.z & 1) << 14)| ((unsigned)(v3.w & 1) << 15);
        *(unsigned short*)&smem[r * mstride + chunk * 2] = (unsigned short)m;
      }
    }
  }
  __syncthreads();

  // ---- phase 1 ----
  const int rb = ih * 32;
  const float wh1a = wh1l[i0 + rb + l15];
  const float wh1b = wh1l[i0 + rb + 16 + l15];
  const char* mrowa = smem + (rb + l15) * mstride;
  const char* mrowb = smem + (rb + 16 + l15) * mstride;
  const unsigned short* bptr = fragB + (size_t)(jbase >> 6) * 8192 + ch * 4096 + lane * 8;
  const float* w2ptr = wh2l + jbase + lg * 8;

  f32x4 acc[2][4] = {};
  f32x4 accs[2] = {};
  short8 onesf;
#pragma unroll
  for (int e = 0; e < 8; ++e) onesf[e] = (short)0x3F80;  // bf16 1.0

  uint2 m2a = *(const uint2*)&mrowa[0];
  uint2 m2b = *(const uint2*)&mrowb[0];
  short8 bf[8];
#pragma unroll
  for (int ks = 0; ks < 2; ++ks)
#pragma unroll
    for (int cgl = 0; cgl < 4; ++cgl)
      bf[ks * 4 + cgl] = *(const short8*)(bptr + cgl * 1024 + ks * 512);
  bptr += 8192;

  for (int it = 0; it < ntiles; ++it) {
    const unsigned int m16a = ((m2a.x >> (8 * lg)) & 0xFFu) |
                              (((m2a.y >> (8 * lg)) & 0xFFu) << 8);
    const unsigned int m16b = ((m2b.x >> (8 * lg)) & 0xFFu) |
                              (((m2b.y >> (8 * lg)) & 0xFFu) << 8);
    // wq loads (wh2 is L1-resident; no cross-iter prefetch needed)
    const float4 wq0 = *(const float4*)(w2ptr);
    const float4 wq1 = *(const float4*)(w2ptr + 4);
    const float4 wq2 = *(const float4*)(w2ptr + 32);
    const float4 wq3 = *(const float4*)(w2ptr + 36);
    w2ptr += 64;

    short8 afa[2], afb[2];
#pragma unroll
    for (int ks = 0; ks < 2; ++ks) {
      const float4 wa = ks ? wq2 : wq0;
      const float4 wb = ks ? wq3 : wq1;
      const float w2v[8] = {wa.x, wa.y, wa.z, wa.w, wb.x, wb.y, wb.z, wb.w};
      union { short8 s8; unsigned int u[4]; } pka, pkb;
#pragma unroll
      for (int e = 0; e < 4; ++e) {
        const float x0 = wh1a + w2v[2 * e];
        const float x1 = wh1a + w2v[2 * e + 1];
        const float y0 = wh1b + w2v[2 * e];
        const float y1 = wh1b + w2v[2 * e + 1];
        const float lx0 = fmaxf(x0, 0.01f * x0);
        const float lx1 = fmaxf(x1, 0.01f * x1);
        const float ly0 = fmaxf(y0, 0.01f * y0);
        const float ly1 = fmaxf(y1, 0.01f * y1);
        float px0 = __builtin_amdgcn_exp2f(lx0);
        float px1 = __builtin_amdgcn_exp2f(lx1);
        float py0 = __builtin_amdgcn_exp2f(ly0);
        float py1 = __builtin_amdgcn_exp2f(ly1);
        px0 = ((m16a >> (ks * 8 + 2 * e)) & 1u) ? px0 : 0.f;
        px1 = ((m16a >> (ks * 8 + 2 * e + 1)) & 1u) ? px1 : 0.f;
        py0 = ((m16b >> (ks * 8 + 2 * e)) & 1u) ? py0 : 0.f;
        py1 = ((m16b >> (ks * 8 + 2 * e + 1)) & 1u) ? py1 : 0.f;
        pka.u[e] = pkbf2(px0, px1);
        pkb.u[e] = pkbf2(py0, py1);
      }
      afa[ks] = pka.s8;
      afb[ks] = pkb.s8;
    }
    // prefetch next tile's masks (LDS latency is the chain head)
    if (it + 1 < ntiles) {
      m2a = *(const uint2*)&mrowa[(it + 1) * 8];
      m2b = *(const uint2*)&mrowb[(it + 1) * 8];
    }
    // MFMAs: 2 rowgroups x 4 col-groups x 2 ks + ones-column row-sums
#pragma unroll
    for (int ks = 0; ks < 2; ++ks) {
      acc[0][0] = __builtin_amdgcn_mfma_f32_16x16x32_bf16(afa[ks], bf[ks * 4 + 0], acc[0][0], 0, 0, 0);
      acc[0][1] = __builtin_amdgcn_mfma_f32_16x16x32_bf16(afa[ks], bf[ks * 4 + 1], acc[0][1], 0, 0, 0);
      acc[0][2] = __builtin_amdgcn_mfma_f32_16x16x32_bf16(afa[ks], bf[ks * 4 + 2], acc[0][2], 0, 0, 0);
      acc[0][3] = __builtin_amdgcn_mfma_f32_16x16x32_bf16(afa[ks], bf[ks * 4 + 3], acc[0][3], 0, 0, 0);
      accs[0]   = __builtin_amdgcn_mfma_f32_16x16x32_bf16(afa[ks], onesf, accs[0], 0, 0, 0);
      acc[1][0] = __builtin_amdgcn_mfma_f32_16x16x32_bf16(afb[ks], bf[ks * 4 + 0], acc[1][0], 0, 0, 0);
      acc[1][1] = __builtin_amdgcn_mfma_f32_16x16x32_bf16(afb[ks], bf[ks * 4 + 1], acc[1][1], 0, 0, 0);
      acc[1][2] = __builtin_amdgcn_mfma_f32_16x16x32_bf16(afb[ks], bf[ks * 4 + 2], acc[1][2], 0, 0, 0);
      acc[1][3] = __builtin_amdgcn_mfma_f32_16x16x32_bf16(afb[ks], bf[ks * 4 + 3], acc[1][3], 0, 0, 0);
      accs[1]   = __builtin_amdgcn_mfma_f32_16x16x32_bf16(afb[ks], onesf, accs[1], 0, 0, 0);
    }
    // prefetch next tile's B fragments
    if (it + 1 < ntiles) {
#pragma unroll
      for (int ks = 0; ks < 2; ++ks)
#pragma unroll
        for (int cgl = 0; cgl < 4; ++cgl)
          bf[ks * 4 + cgl] = *(const short8*)(bptr + cgl * 1024 + ks * 512);
      bptr += 8192;
    }
  }

  // psum via ones-column: lane(l15=0,lg) reg r holds rowsum[rg*16 + lg*4 + r]
  if (ch == 0 && l15 == 0) {
#pragma unroll
    for (int rg = 0; rg < 2; ++rg)
#pragma unroll
      for (int r = 0; r < 4; ++r)
        psum_p[(size_t)blockIdx.y * NV + i0 + rb + rg * 16 + lg * 4 + r] = accs[rg][r];
  }

  // unnormalized partial tiles (C/D: col=l15, row=lg*4+r)
#pragma unroll
  for (int rg = 0; rg < 2; ++rg) {
    const size_t ob = ((size_t)blockIdx.y * NV + i0 + rb + rg * 16) * MOUT + ch * 64;
#pragma unroll
    for (int cgl = 0; cgl < 4; ++cgl)
#pragma unroll
      for (int r = 0; r < 4; ++r)
        out_p[ob + (size_t)(lg * 4 + r) * MOUT + cgl * 16 + l15] = acc[rg][cgl][r];
  }
}

// ---------------- kernel 3: combine partials, normalize, ELU ----------------
__global__ __launch_bounds__(256) void k_comb(const float* __restrict__ out_p,
                                              const float* __restrict__ psum_p,
                                              float* __restrict__ out, int S) {
  const int idx = (blockIdx.x * 256 + threadIdx.x) * 4;
  const int n = idx >> 7;  // MOUT = 128
  float denom = 0.f;
  for (int s = 0; s < S; ++s) denom += psum_p[(size_t)s * NV + n];
  float4 acc = {0.f, 0.f, 0.f, 0.f};
  for (int s = 0; s < S; ++s) {
    const float4 v = *(const float4*)&out_p[(size_t)s * NV * MOUT + idx];
    acc.x += v.x; acc.y += v.y; acc.z += v.z; acc.w += v.w;
  }
  const float inv = 1.f / denom;
  float4 o;
  o.x = elu1(acc.x * inv);
  o.y = elu1(acc.y * inv);
  o.z = elu1(acc.z * inv);
  o.w = elu1(acc.w * inv);
  *(float4*)&out[idx] = o;
}

extern "C" void kernel_launch(void* const* d_in, const int* in_sizes, int n_in,
                              void* d_out, int out_size, void* d_ws, size_t ws_size,
                              hipStream_t stream) {
  const float* h  = (const float*)d_in[0];
  const int* adj  = (const int*)d_in[1];
  const float* w  = (const float*)d_in[2];
  const float* a1 = (const float*)d_in[3];
  const float* a2 = (const float*)d_in[4];
  float* out = (float*)d_out;

  char* ws = (char*)d_ws;
  // layout: [fragB 2MB][wh1 32KB][wh2 32KB][psum_p 256KB][out_p S*4MB]
  unsigned short* fragB = (unsigned short*)ws;
  size_t off = (size_t)MOUT * NV * 2;
  float* wh1 = (float*)(ws + off); off += (size_t)NV * 4;
  float* wh2 = (float*)(ws + off); off += (size_t)NV * 4;
  float* psum_p = (float*)(ws + off); off += (size_t)8 * NV * 4;
  float* out_p = (float*)(ws + off);

  int S = 8;
  while (S > 1 && off + (size_t)S * NV * MOUT * 4 > ws_size) S >>= 1;
  const int ntiles = 128 / S;
  const size_t smbytes = (size_t)64 * (ntiles * 8 + 8);

  k_wh<<<NV / 32, 256, 0, stream>>>(h, w, a1, a2, fragB, wh1, wh2);
  k_attn_p<<<dim3(NV / 64, S), 256, smbytes, stream>>>(fragB, adj, wh1, wh2, out_p, psum_p, ntiles);
  k_comb<<<(NV * MOUT / 4) / 256, 256, 0, stream>>>(out_p, psum_p, out, S);
}